// Round 3
// baseline (240.039 us; speedup 1.0000x reference)
//
#include <hip/hip_runtime.h>

// Derivative1D: y[b, i, c] = x[b, i+1, c] - x[b, i, c]
// x: (B=64, L=16384, C=32) fp32; y: (B, L-1, C) fp32.
// Flat per batch: out[r] = x[r + C] - x[r], r in [0, (L-1)*C).
//
// R3: fully-resident grid (1024 blocks = 4/CU, no dispatch ramp),
// software-pipelined passes (next pass's loads in flight while storing
// current), nontemporal stores (output is write-once -> don't pollute L3,
// let the 256 MiB L3 hold the whole 128 MiB input).

typedef float v4f __attribute__((ext_vector_type(4)));

constexpr int B = 64;
constexpr int L = 16384;
constexpr int C = 32;
constexpr int IN_PER_BATCH = L * C;            // 524288 floats
constexpr int OUT_PER_BATCH = (L - 1) * C;     // 524256 floats
constexpr int OUT4 = OUT_PER_BATCH / 4;        // 131064 float4 per batch
constexpr int BLOCK = 256;
constexpr int BLOCKS_PER_BATCH = 16;           // grid.x
constexpr int REGION = 8192;                   // float4 per block (16*8192 >= 131064)
constexpr int U = 4;                           // float4 per thread per pass
constexpr int PASS = REGION / (BLOCK * U);     // 8 passes

__global__ __launch_bounds__(BLOCK) void deriv1d_kernel(const float* __restrict__ x,
                                                        float* __restrict__ out) {
    const int b = blockIdx.y;
    const float* xb = x + (size_t)b * IN_PER_BATCH;
    float* ob = out + (size_t)b * OUT_PER_BATCH;
    const int region = blockIdx.x * REGION;

    v4f cur_a[U], cur_n[U];
    int cur_r4[U];

    // Prologue: issue pass-0 loads.
#pragma unroll
    for (int u = 0; u < U; ++u) {
        int r4 = region + u * BLOCK + threadIdx.x;
        cur_r4[u] = r4;
        if (r4 < OUT4) {
            cur_a[u] = *(const v4f*)(xb + (size_t)r4 * 4);
            cur_n[u] = *(const v4f*)(xb + (size_t)r4 * 4 + C);
        }
    }

    for (int p = 1; p <= PASS; ++p) {
        v4f nxt_a[U], nxt_n[U];
        int nxt_r4[U];
        // Issue next pass's loads BEFORE consuming current pass (keeps
        // reads continuously outstanding; compiler orders via vmcnt).
        if (p < PASS) {
#pragma unroll
            for (int u = 0; u < U; ++u) {
                int r4 = region + (p * U + u) * BLOCK + threadIdx.x;
                nxt_r4[u] = r4;
                if (r4 < OUT4) {
                    nxt_a[u] = *(const v4f*)(xb + (size_t)r4 * 4);
                    nxt_n[u] = *(const v4f*)(xb + (size_t)r4 * 4 + C);
                }
            }
        }
        // Compute + nontemporal store for current pass.
#pragma unroll
        for (int u = 0; u < U; ++u) {
            int r4 = cur_r4[u];
            if (r4 < OUT4) {
                v4f d = cur_n[u] - cur_a[u];
                __builtin_nontemporal_store(d, (v4f*)(ob + (size_t)r4 * 4));
            }
        }
#pragma unroll
        for (int u = 0; u < U; ++u) {
            cur_a[u] = nxt_a[u];
            cur_n[u] = nxt_n[u];
            cur_r4[u] = nxt_r4[u];
        }
    }
}

extern "C" void kernel_launch(void* const* d_in, const int* in_sizes, int n_in,
                              void* d_out, int out_size, void* d_ws, size_t ws_size,
                              hipStream_t stream) {
    const float* x = (const float*)d_in[0];
    float* out = (float*)d_out;

    dim3 grid(BLOCKS_PER_BATCH, B);   // (16, 64) = 1024 blocks = 4/CU, fully resident
    dim3 block(BLOCK);
    deriv1d_kernel<<<grid, block, 0, stream>>>(x, out);
}